// Round 1
// baseline (3943.332 us; speedup 1.0000x reference)
//
#include <hip/hip_runtime.h>
#include <hip/hip_bf16.h>

// Problem dims (fixed by reference)
constexpr int N_ = 64, C_ = 512, T_ = 1024;
constexpr int NT_ = N_ * T_;        // 65536 rows
constexpr int K_ = 1024;            // nb_code
constexpr int A_ = 512;             // attn_dim

// Output layout (floats, concatenated in return order)
constexpr size_t XD_OFF   = 0;                       // 33554432
constexpr size_t SC_OFF   = (size_t)N_ * C_ * T_;    // 5 scalars
constexpr size_t CODE_OFF = SC_OFF + 5;              // 65536 code_idx as float

// Workspace layout (floats)
constexpr size_t QT_OFF   = 0;                        // qT[A_][NT_] (transposed!)
constexpr size_t KNT_OFF  = (size_t)A_ * NT_;         // knT[A_][K_]
constexpr size_t AVG_OFF  = KNT_OFF + (size_t)A_ * K_;
constexpr size_t CNT_OFF  = AVG_OFF + K_;
constexpr size_t SCAL_OFF = CNT_OFF + K_;             // [0]=ent_sum, [1]=vq_sum

__device__ __forceinline__ unsigned short f2bf(float f) {
  unsigned int u = __float_as_uint(f);
  unsigned int r = (u + 0x7fffu + ((u >> 16) & 1u)) >> 16;
  return (unsigned short)r;
}
__device__ __forceinline__ float bf2f(unsigned short s) {
  return __uint_as_float(((unsigned int)s) << 16);
}

__global__ __launch_bounds__(256) void init_kernel(float* p) {
  int i = blockIdx.x * 256 + threadIdx.x;
  if (i < 2050) p[i] = 0.f;   // avg_probs(1024) + counts(1024) + 2 scalars
}

// k = l2norm(codebook @ Wk) / sqrt(A), stored transposed: knT[j][kk]
__global__ __launch_bounds__(256) void knorm_kernel(const float* __restrict__ cb,
                                                    const float* __restrict__ Wk,
                                                    float* __restrict__ knT) {
  __shared__ float cb_s[4][A_];
  __shared__ float norm_s[4];
  int tid = threadIdx.x;
  int r0 = blockIdx.x * 4;
  for (int i = tid; i < 4 * A_; i += 256) {
    int r = i >> 9, c = i & 511;
    cb_s[r][c] = cb[(size_t)(r0 + r) * C_ + c];
  }
  if (tid < 4) norm_s[tid] = 0.f;
  __syncthreads();
  float acc[4][2] = {};
  for (int c = 0; c < C_; ++c) {
    float w0 = Wk[(size_t)c * A_ + tid];
    float w1 = Wk[(size_t)c * A_ + tid + 256];
#pragma unroll
    for (int r = 0; r < 4; ++r) {
      float xv = cb_s[r][c];
      acc[r][0] += xv * w0;
      acc[r][1] += xv * w1;
    }
  }
#pragma unroll
  for (int r = 0; r < 4; ++r) {
    float ss = acc[r][0] * acc[r][0] + acc[r][1] * acc[r][1];
#pragma unroll
    for (int off = 32; off > 0; off >>= 1) ss += __shfl_down(ss, off, 64);
    if ((tid & 63) == 0) atomicAdd(&norm_s[r], ss);
  }
  __syncthreads();
  const float inv_sqrtA = 0.0441941738241592f;  // 1/sqrt(512)
#pragma unroll
  for (int r = 0; r < 4; ++r) {
    float scale = inv_sqrtA / (sqrtf(norm_s[r]) + 1e-8f);
    knT[(size_t)tid * K_ + r0 + r] = acc[r][0] * scale;
    knT[(size_t)(tid + 256) * K_ + r0 + r] = acc[r][1] * scale;
  }
}

// q = l2norm(xf @ Wq), stored transposed: qT[j][row].  32 rows/block.
__global__ __launch_bounds__(256, 2) void q_kernel(const float* __restrict__ x,
                                                   const float* __restrict__ Wq,
                                                   float* __restrict__ qT) {
  __shared__ float xf_sT[32][32];   // [c][row]
  __shared__ float Wq_s[32][512];   // 64 KB
  int tid = threadIdx.x;
  int wv = tid >> 6, lane = tid & 63;
  int r0 = blockIdx.x * 32;
  int n = r0 >> 10, t0 = r0 & 1023;
  float acc[8][8] = {};             // 8 rows (wv*8+i) x 8 j (lane*4+jl, +256)
  for (int c0 = 0; c0 < C_; c0 += 32) {
    __syncthreads();
    {
      int ci = tid >> 3;
      int r4 = (tid & 7) * 4;
      const float* src = &x[(size_t)n * C_ * T_ + (size_t)(c0 + ci) * T_ + t0 + r4];
      float4 v = *(const float4*)src;
      xf_sT[ci][r4 + 0] = v.x; xf_sT[ci][r4 + 1] = v.y;
      xf_sT[ci][r4 + 2] = v.z; xf_sT[ci][r4 + 3] = v.w;
    }
    for (int i = tid * 4; i < 32 * 512; i += 1024) {
      int cc = i >> 9, j = i & 511;
      *(float4*)&Wq_s[cc][j] = *(const float4*)&Wq[(size_t)(c0 + cc) * A_ + j];
    }
    __syncthreads();
#pragma unroll
    for (int cc = 0; cc < 32; ++cc) {
      float xr[8], wr[8];
      *(float4*)&xr[0] = *(float4*)&xf_sT[cc][wv * 8];
      *(float4*)&xr[4] = *(float4*)&xf_sT[cc][wv * 8 + 4];
      *(float4*)&wr[0] = *(float4*)&Wq_s[cc][lane * 4];
      *(float4*)&wr[4] = *(float4*)&Wq_s[cc][lane * 4 + 256];
#pragma unroll
      for (int i = 0; i < 8; ++i)
#pragma unroll
        for (int j = 0; j < 8; ++j) acc[i][j] += xr[i] * wr[j];
    }
  }
  float scale[8];
#pragma unroll
  for (int i = 0; i < 8; ++i) {
    float ss = 0.f;
#pragma unroll
    for (int j = 0; j < 8; ++j) ss += acc[i][j] * acc[i][j];
#pragma unroll
    for (int off = 1; off < 64; off <<= 1) ss += __shfl_xor(ss, off, 64);
    scale[i] = 1.0f / (sqrtf(ss) + 1e-8f);
  }
#pragma unroll
  for (int j = 0; j < 8; ++j) {
    int jj = (j < 4) ? (lane * 4 + j) : (256 + lane * 4 + (j - 4));
    float4 v0 = make_float4(acc[0][j] * scale[0], acc[1][j] * scale[1],
                            acc[2][j] * scale[2], acc[3][j] * scale[3]);
    float4 v1 = make_float4(acc[4][j] * scale[4], acc[5][j] * scale[5],
                            acc[6][j] * scale[6], acc[7][j] * scale[7]);
    float* dst = &qT[(size_t)jj * NT_ + r0 + wv * 8];
    *(float4*)dst = v0;
    *(float4*)(dst + 4) = v1;
  }
}

// Fused: logits (fp32) -> argmax/softmax x2/stats -> z_q (bf16 attn, fp32 acc) -> x_d
__global__ __launch_bounds__(256, 2) void fused_kernel(
    const float* __restrict__ x, const float* __restrict__ qT,
    const float* __restrict__ knT, const float* __restrict__ cb,
    float* __restrict__ out, float* __restrict__ avg_probs,
    float* __restrict__ counts, float* __restrict__ scal) {
  __shared__ float k_sT[8][K_];      // 32 KB; reused as attn_s[16][1024] bf16
  __shared__ float cb_s[16][512];    // 32 KB
  __shared__ float q_sT[8][16];
  __shared__ float avg_s[K_];        // 4 KB
  __shared__ float red_s[2];
  unsigned short* attn_s = (unsigned short*)&k_sT[0][0];

  int tid = threadIdx.x;
  int wv = tid >> 6, lane = tid & 63;
  int r0 = blockIdx.x * 16;
  int n = r0 >> 10, t0 = r0 & 1023;

  for (int i = tid; i < K_; i += 256) avg_s[i] = 0.f;
  if (tid < 2) red_s[tid] = 0.f;

  // ---- Phase A: logits[16][1024] fp32, acc[i][kj*4+kl] for kk = lane*4+kl+256*kj
  float acc[4][16] = {};
  for (int j0 = 0; j0 < A_; j0 += 8) {
    __syncthreads();
    for (int i = tid * 4; i < 8 * K_; i += 1024) {
      int jj = i >> 10, kk = i & 1023;
      *(float4*)&k_sT[jj][kk] = *(const float4*)&knT[(size_t)(j0 + jj) * K_ + kk];
    }
    if (tid < 128) {
      int jj = tid >> 4, r = tid & 15;
      q_sT[jj][r] = qT[(size_t)(j0 + jj) * NT_ + r0 + r];
    }
    __syncthreads();
#pragma unroll
    for (int jj = 0; jj < 8; ++jj) {
      float qr[4], kr[16];
      *(float4*)&qr[0] = *(float4*)&q_sT[jj][wv * 4];
#pragma unroll
      for (int kj = 0; kj < 4; ++kj)
        *(float4*)&kr[kj * 4] = *(float4*)&k_sT[jj][lane * 4 + kj * 256];
#pragma unroll
      for (int i = 0; i < 4; ++i)
#pragma unroll
        for (int k = 0; k < 16; ++k) acc[i][k] += qr[i] * kr[k];
    }
  }
  __syncthreads();   // all k_sT reads done before attn_s overwrite

  // ---- Per-row stats (rows fully owned by one wave -> shuffle reductions)
  float entp = 0.f;
  float p_loc[16] = {};
#pragma unroll
  for (int i = 0; i < 4; ++i) {
    int row_l = wv * 4 + i;
    float m = acc[i][0];
    int bidx = lane * 4;
#pragma unroll
    for (int kj = 0; kj < 4; ++kj)
#pragma unroll
      for (int kl = 0; kl < 4; ++kl) {
        float v = acc[i][kj * 4 + kl];
        int kk = lane * 4 + kl + 256 * kj;
        if (v > m || (v == m && kk < bidx)) { m = v; bidx = kk; }
      }
#pragma unroll
    for (int off = 1; off < 64; off <<= 1) {
      float vm = __shfl_xor(m, off, 64);
      int vi = __shfl_xor(bidx, off, 64);
      if (vm > m || (vm == m && vi < bidx)) { m = vm; bidx = vi; }
    }
    float S1 = 0.f, S100 = 0.f, U100 = 0.f;
#pragma unroll
    for (int k = 0; k < 16; ++k) {
      float e = acc[i][k] - m;
      S1 += __expf(e);
      float e100 = e * 100.0f;
      float p = __expf(e100);
      S100 += p;
      U100 += p * e100;
    }
#pragma unroll
    for (int off = 1; off < 64; off <<= 1) {
      S1 += __shfl_xor(S1, off, 64);
      S100 += __shfl_xor(S100, off, 64);
      U100 += __shfl_xor(U100, off, 64);
    }
    float invS1 = 1.0f / S1;
    float invS100 = 1.0f / S100;
    if (lane == 0) {
      out[CODE_OFF + r0 + row_l] = (float)bidx;
      atomicAdd(&counts[bidx], 1.0f);
      entp += __logf(S100) - U100 * invS100;  // row entropy
    }
#pragma unroll
    for (int kj = 0; kj < 4; ++kj) {
      ushort4 pk;
      float e0 = acc[i][kj * 4 + 0] - m, e1 = acc[i][kj * 4 + 1] - m;
      float e2 = acc[i][kj * 4 + 2] - m, e3 = acc[i][kj * 4 + 3] - m;
      pk.x = f2bf(__expf(e0) * invS1); pk.y = f2bf(__expf(e1) * invS1);
      pk.z = f2bf(__expf(e2) * invS1); pk.w = f2bf(__expf(e3) * invS1);
      *(ushort4*)&attn_s[(size_t)row_l * K_ + lane * 4 + kj * 256] = pk;
      p_loc[kj * 4 + 0] += __expf(e0 * 100.f) * invS100;
      p_loc[kj * 4 + 1] += __expf(e1 * 100.f) * invS100;
      p_loc[kj * 4 + 2] += __expf(e2 * 100.f) * invS100;
      p_loc[kj * 4 + 3] += __expf(e3 * 100.f) * invS100;
    }
  }
#pragma unroll
  for (int kj = 0; kj < 4; ++kj)
#pragma unroll
    for (int kl = 0; kl < 4; ++kl)
      atomicAdd(&avg_s[lane * 4 + kl + 256 * kj], p_loc[kj * 4 + kl]);
  if (lane == 0) atomicAdd(&red_s[0], entp);

  // ---- Phase B: z_q = attn_w @ codebook, c = lane*4+cl+256*cj
  float acc2[4][8] = {};
  for (int kk0 = 0; kk0 < K_; kk0 += 16) {
    __syncthreads();
    for (int i = tid * 4; i < 16 * 512; i += 1024) {
      int kki = i >> 9, c = i & 511;
      *(float4*)&cb_s[kki][c] = *(const float4*)&cb[(size_t)(kk0 + kki) * C_ + c];
    }
    __syncthreads();
#pragma unroll
    for (int kki = 0; kki < 16; ++kki) {
      float a[4];
#pragma unroll
      for (int i = 0; i < 4; ++i)
        a[i] = bf2f(attn_s[(size_t)(wv * 4 + i) * K_ + kk0 + kki]);
      float b[8];
      *(float4*)&b[0] = *(float4*)&cb_s[kki][lane * 4];
      *(float4*)&b[4] = *(float4*)&cb_s[kki][lane * 4 + 256];
#pragma unroll
      for (int i = 0; i < 4; ++i)
#pragma unroll
        for (int c = 0; c < 8; ++c) acc2[i][c] += a[i] * b[c];
    }
  }

  // ---- Epilogue: vq partial + x_d writes (L2 merges the 64B lines)
  float vqp = 0.f;
#pragma unroll
  for (int i = 0; i < 4; ++i) {
    int t = t0 + wv * 4 + i;
#pragma unroll
    for (int cj = 0; cj < 2; ++cj)
#pragma unroll
      for (int cl = 0; cl < 4; ++cl) {
        int c = lane * 4 + cl + 256 * cj;
        size_t xi = (size_t)n * C_ * T_ + (size_t)c * T_ + t;
        float xf = x[xi];
        float d = acc2[i][cj * 4 + cl] - xf;
        vqp += d * d;
        out[XD_OFF + xi] = xf + d;
      }
  }
#pragma unroll
  for (int off = 1; off < 64; off <<= 1) vqp += __shfl_xor(vqp, off, 64);
  if (lane == 0) atomicAdd(&red_s[1], vqp);
  __syncthreads();
  if (tid == 0) {
    atomicAdd(&scal[0], red_s[0]);
    atomicAdd(&scal[1], red_s[1]);
  }
  for (int i = tid; i < K_; i += 256) atomicAdd(&avg_probs[i], avg_s[i]);
}

__global__ __launch_bounds__(1024) void finalize_kernel(const float* __restrict__ avgp,
                                                        const float* __restrict__ counts,
                                                        const float* __restrict__ scal,
                                                        float* __restrict__ out) {
  __shared__ float r1[16], r2[16];
  int tid = threadIdx.x;
  float a = avgp[tid] * (1.0f / 65536.0f);
  float t1 = a * logf(a + 1e-5f);
  float p = counts[tid] * (1.0f / 65536.0f);
  float t2 = p * logf(p + 1e-7f);
#pragma unroll
  for (int off = 1; off < 64; off <<= 1) {
    t1 += __shfl_xor(t1, off, 64);
    t2 += __shfl_xor(t2, off, 64);
  }
  int wv = tid >> 6, lane = tid & 63;
  if (lane == 0) { r1[wv] = t1; r2[wv] = t2; }
  __syncthreads();
  if (tid == 0) {
    float T1 = 0.f, T2 = 0.f;
    for (int i = 0; i < 16; ++i) { T1 += r1[i]; T2 += r2[i]; }
    float sample_entropy = scal[0] * (1.0f / 65536.0f);
    float avg_entropy = -T1;
    out[SC_OFF + 0] = sample_entropy;
    out[SC_OFF + 1] = avg_entropy;
    out[SC_OFF + 2] = sample_entropy - avg_entropy;
    out[SC_OFF + 3] = expf(-T2);
    out[SC_OFF + 4] = scal[1] * (1.0f / 33554432.0f);
  }
}

extern "C" void kernel_launch(void* const* d_in, const int* in_sizes, int n_in,
                              void* d_out, int out_size, void* d_ws, size_t ws_size,
                              hipStream_t stream) {
  const float* x  = (const float*)d_in[0];
  const float* cb = (const float*)d_in[1];
  const float* Wq = (const float*)d_in[2];
  const float* Wk = (const float*)d_in[3];
  float* out = (float*)d_out;
  float* ws = (float*)d_ws;
  float* qT     = ws + QT_OFF;
  float* knT    = ws + KNT_OFF;
  float* avgp   = ws + AVG_OFF;
  float* counts = ws + CNT_OFF;
  float* scal   = ws + SCAL_OFF;

  init_kernel<<<9, 256, 0, stream>>>(avgp);
  knorm_kernel<<<K_ / 4, 256, 0, stream>>>(cb, Wk, knT);
  q_kernel<<<NT_ / 32, 256, 0, stream>>>(x, Wq, qT);
  fused_kernel<<<NT_ / 16, 256, 0, stream>>>(x, qT, knT, cb, out, avgp, counts, scal);
  finalize_kernel<<<1, 1024, 0, stream>>>(avgp, counts, scal, out);
}

// Round 2
// 2176.378 us; speedup vs baseline: 1.8119x; 1.8119x over previous
//
#include <hip/hip_runtime.h>
#include <hip/hip_bf16.h>

// Problem dims (fixed by reference)
constexpr int N_ = 64, C_ = 512, T_ = 1024;
constexpr int NT_ = N_ * T_;        // 65536 rows
constexpr int K_ = 1024;            // nb_code
constexpr int A_ = 512;             // attn_dim

// Output layout (floats, concatenated in return order)
constexpr size_t XD_OFF   = 0;                       // 33554432
constexpr size_t SC_OFF   = (size_t)N_ * C_ * T_;    // 5 scalars
constexpr size_t CODE_OFF = SC_OFF + 5;              // 65536 code_idx as float

// Workspace layout (floats).  q fp32 [NT][512] occupies the SAME bytes as
// attn bf16 [NT][1024] (2 KB/row each) — logits_kernel reads its own q rows,
// then overwrites them with attn (row-aligned alias, no cross-block hazard).
// cbT bf16 [512][1024] aliases the knT region (knT dead after logits_kernel).
constexpr size_t Q_OFF    = 0;
constexpr size_t KNT_OFF  = (size_t)NT_ * A_;         // 33554432
constexpr size_t AVG_OFF  = KNT_OFF + (size_t)A_ * K_;
constexpr size_t CNT_OFF  = AVG_OFF + K_;
constexpr size_t SCAL_OFF = CNT_OFF + K_;             // [0]=ent_sum, [1]=vq_sum

typedef __attribute__((ext_vector_type(8))) short short8;
typedef __attribute__((ext_vector_type(4))) float f32x4;

__device__ __forceinline__ unsigned short f2bf(float f) {
  unsigned int u = __float_as_uint(f);
  unsigned int r = (u + 0x7fffu + ((u >> 16) & 1u)) >> 16;
  return (unsigned short)r;
}

__global__ __launch_bounds__(256) void init_kernel(float* p) {
  int i = blockIdx.x * 256 + threadIdx.x;
  if (i < 2050) p[i] = 0.f;   // avg_probs(1024) + counts(1024) + 2 scalars
}

// k = l2norm(codebook @ Wk) / sqrt(A), stored transposed: knT[j][kk]
__global__ __launch_bounds__(256) void knorm_kernel(const float* __restrict__ cb,
                                                    const float* __restrict__ Wk,
                                                    float* __restrict__ knT) {
  __shared__ float cb_s[4][A_];
  __shared__ float norm_s[4];
  int tid = threadIdx.x;
  int r0 = blockIdx.x * 4;
  for (int i = tid; i < 4 * A_; i += 256) {
    int r = i >> 9, c = i & 511;
    cb_s[r][c] = cb[(size_t)(r0 + r) * C_ + c];
  }
  if (tid < 4) norm_s[tid] = 0.f;
  __syncthreads();
  float acc[4][2] = {};
  for (int c = 0; c < C_; ++c) {
    float w0 = Wk[(size_t)c * A_ + tid];
    float w1 = Wk[(size_t)c * A_ + tid + 256];
#pragma unroll
    for (int r = 0; r < 4; ++r) {
      float xv = cb_s[r][c];
      acc[r][0] += xv * w0;
      acc[r][1] += xv * w1;
    }
  }
#pragma unroll
  for (int r = 0; r < 4; ++r) {
    float ss = acc[r][0] * acc[r][0] + acc[r][1] * acc[r][1];
#pragma unroll
    for (int off = 32; off > 0; off >>= 1) ss += __shfl_down(ss, off, 64);
    if ((tid & 63) == 0) atomicAdd(&norm_s[r], ss);
  }
  __syncthreads();
  const float inv_sqrtA = 0.0441941738241592f;  // 1/sqrt(512)
#pragma unroll
  for (int r = 0; r < 4; ++r) {
    float scale = inv_sqrtA / (sqrtf(norm_s[r]) + 1e-8f);
    knT[(size_t)tid * K_ + r0 + r] = acc[r][0] * scale;
    knT[(size_t)(tid + 256) * K_ + r0 + r] = acc[r][1] * scale;
  }
}

// q = l2norm(xf @ Wq), row-major: q[row][j].  32 rows/block.
__global__ __launch_bounds__(256, 2) void q_kernel(const float* __restrict__ x,
                                                   const float* __restrict__ Wq,
                                                   float* __restrict__ q) {
  __shared__ float xf_sT[32][32];   // [c][row]
  __shared__ float Wq_s[32][512];   // 64 KB
  int tid = threadIdx.x;
  int wv = tid >> 6, lane = tid & 63;
  int r0 = blockIdx.x * 32;
  int n = r0 >> 10, t0 = r0 & 1023;
  float acc[8][8] = {};             // 8 rows (wv*8+i) x 8 j (lane*4+jl, +256)
  for (int c0 = 0; c0 < C_; c0 += 32) {
    __syncthreads();
    {
      int ci = tid >> 3;
      int r4 = (tid & 7) * 4;
      const float* src = &x[(size_t)n * C_ * T_ + (size_t)(c0 + ci) * T_ + t0 + r4];
      float4 v = *(const float4*)src;
      xf_sT[ci][r4 + 0] = v.x; xf_sT[ci][r4 + 1] = v.y;
      xf_sT[ci][r4 + 2] = v.z; xf_sT[ci][r4 + 3] = v.w;
    }
    for (int i = tid * 4; i < 32 * 512; i += 1024) {
      int cc = i >> 9, j = i & 511;
      *(float4*)&Wq_s[cc][j] = *(const float4*)&Wq[(size_t)(c0 + cc) * A_ + j];
    }
    __syncthreads();
#pragma unroll
    for (int cc = 0; cc < 32; ++cc) {
      float xr[8], wr[8];
      *(float4*)&xr[0] = *(float4*)&xf_sT[cc][wv * 8];
      *(float4*)&xr[4] = *(float4*)&xf_sT[cc][wv * 8 + 4];
      *(float4*)&wr[0] = *(float4*)&Wq_s[cc][lane * 4];
      *(float4*)&wr[4] = *(float4*)&Wq_s[cc][lane * 4 + 256];
#pragma unroll
      for (int i = 0; i < 8; ++i)
#pragma unroll
        for (int j = 0; j < 8; ++j) acc[i][j] += xr[i] * wr[j];
    }
  }
  float scale[8];
#pragma unroll
  for (int i = 0; i < 8; ++i) {
    float ss = 0.f;
#pragma unroll
    for (int j = 0; j < 8; ++j) ss += acc[i][j] * acc[i][j];
#pragma unroll
    for (int off = 1; off < 64; off <<= 1) ss += __shfl_xor(ss, off, 64);
    scale[i] = 1.0f / (sqrtf(ss) + 1e-8f);
  }
#pragma unroll
  for (int i = 0; i < 8; ++i) {
    float4 v0 = make_float4(acc[i][0] * scale[i], acc[i][1] * scale[i],
                            acc[i][2] * scale[i], acc[i][3] * scale[i]);
    float4 v1 = make_float4(acc[i][4] * scale[i], acc[i][5] * scale[i],
                            acc[i][6] * scale[i], acc[i][7] * scale[i]);
    float* dst = &q[(size_t)(r0 + wv * 8 + i) * A_];
    *(float4*)(dst + lane * 4) = v0;
    *(float4*)(dst + lane * 4 + 256) = v1;
  }
}

// logits (fp32, 32 rows/block, 8 rows/wave) -> argmax/softmax x2/stats -> attn bf16 (global)
// NOTE: q and att alias (same buffer) — no __restrict__ on them.
__global__ __launch_bounds__(256, 2) void logits_kernel(
    const float* q, const float* __restrict__ knT, unsigned short* att,
    float* __restrict__ out, float* __restrict__ avg_probs,
    float* __restrict__ counts, float* __restrict__ scal) {
  __shared__ float k_sT[16][K_];    // 64 KB
  __shared__ float q_s[32][16];     // 2 KB
  __shared__ float avg_s[K_];       // 4 KB
  __shared__ float red_s;
  int tid = threadIdx.x;
  int wv = tid >> 6, lane = tid & 63;
  int r0 = blockIdx.x * 32;

  for (int i = tid; i < K_; i += 256) avg_s[i] = 0.f;
  if (tid == 0) red_s = 0.f;

  float acc[8][16] = {};            // rows wv*8+i ; cols lane*4+kl+256*kj
  for (int j0 = 0; j0 < A_; j0 += 16) {
    __syncthreads();
    for (int i = tid * 4; i < 16 * K_; i += 1024) {
      int jj = i >> 10, kk = i & (K_ - 1);
      *(float4*)&k_sT[jj][kk] = *(const float4*)&knT[(size_t)(j0 + jj) * K_ + kk];
    }
    {
      int r = tid >> 3, j2 = (tid & 7) * 2;
      *(float2*)&q_s[r][j2] = *(const float2*)&q[(size_t)(r0 + r) * A_ + j0 + j2];
    }
    __syncthreads();
#pragma unroll 2
    for (int jj = 0; jj < 16; ++jj) {
      float kr[16];
#pragma unroll
      for (int kj = 0; kj < 4; ++kj)
        *(float4*)&kr[kj * 4] = *(float4*)&k_sT[jj][lane * 4 + kj * 256];
      float qv[8];
#pragma unroll
      for (int i = 0; i < 8; ++i) qv[i] = q_s[wv * 8 + i][jj];  // wave-uniform broadcast
#pragma unroll
      for (int i = 0; i < 8; ++i)
#pragma unroll
        for (int k = 0; k < 16; ++k) acc[i][k] += qv[i] * kr[k];
    }
  }

  // ---- Per-row stats (row owned by one wave -> shuffle reductions)
  float entp = 0.f;
  float p_loc[16] = {};
#pragma unroll
  for (int i = 0; i < 8; ++i) {
    int row = r0 + wv * 8 + i;
    float m = acc[i][0];
    int bidx = lane * 4;
#pragma unroll
    for (int kj = 0; kj < 4; ++kj)
#pragma unroll
      for (int kl = 0; kl < 4; ++kl) {
        float v = acc[i][kj * 4 + kl];
        int kk = lane * 4 + kl + 256 * kj;
        if (v > m || (v == m && kk < bidx)) { m = v; bidx = kk; }
      }
#pragma unroll
    for (int off = 1; off < 64; off <<= 1) {
      float vm = __shfl_xor(m, off, 64);
      int vi = __shfl_xor(bidx, off, 64);
      if (vm > m || (vm == m && vi < bidx)) { m = vm; bidx = vi; }
    }
    float S1 = 0.f, S100 = 0.f, U100 = 0.f;
#pragma unroll
    for (int k = 0; k < 16; ++k) {
      float e = acc[i][k] - m;
      S1 += __expf(e);
      float e100 = e * 100.0f;
      float p = __expf(e100);
      S100 += p;
      U100 += p * e100;
    }
#pragma unroll
    for (int off = 1; off < 64; off <<= 1) {
      S1 += __shfl_xor(S1, off, 64);
      S100 += __shfl_xor(S100, off, 64);
      U100 += __shfl_xor(U100, off, 64);
    }
    float invS1 = 1.0f / S1;
    float invS100 = 1.0f / S100;
    if (lane == 0) {
      out[CODE_OFF + row] = (float)bidx;
      atomicAdd(&counts[bidx], 1.0f);
      entp += __logf(S100) - U100 * invS100;  // row entropy
    }
#pragma unroll
    for (int kj = 0; kj < 4; ++kj) {
      ushort4 pk;
      float e0 = acc[i][kj * 4 + 0] - m, e1 = acc[i][kj * 4 + 1] - m;
      float e2 = acc[i][kj * 4 + 2] - m, e3 = acc[i][kj * 4 + 3] - m;
      pk.x = f2bf(__expf(e0) * invS1); pk.y = f2bf(__expf(e1) * invS1);
      pk.z = f2bf(__expf(e2) * invS1); pk.w = f2bf(__expf(e3) * invS1);
      *(ushort4*)&att[(size_t)row * K_ + lane * 4 + kj * 256] = pk;
      p_loc[kj * 4 + 0] += __expf(e0 * 100.f) * invS100;
      p_loc[kj * 4 + 1] += __expf(e1 * 100.f) * invS100;
      p_loc[kj * 4 + 2] += __expf(e2 * 100.f) * invS100;
      p_loc[kj * 4 + 3] += __expf(e3 * 100.f) * invS100;
    }
  }
#pragma unroll
  for (int kj = 0; kj < 4; ++kj)
#pragma unroll
    for (int kl = 0; kl < 4; ++kl)
      atomicAdd(&avg_s[lane * 4 + kl + 256 * kj], p_loc[kj * 4 + kl]);
  if (lane == 0) atomicAdd(&red_s, entp);
  __syncthreads();
  if (tid == 0) atomicAdd(&scal[0], red_s);
  for (int i = tid; i < K_; i += 256) atomicAdd(&avg_probs[i], avg_s[i]);
}

// cbT[c][k] = bf16(cb[k][c]) — B operand for the z_q MFMA
__global__ __launch_bounds__(256) void cbt_kernel(const float* __restrict__ cb,
                                                  unsigned short* __restrict__ cbt) {
  int idx = blockIdx.x * 256 + threadIdx.x;   // 524288 total
  int c = idx >> 10, k = idx & 1023;
  cbt[(size_t)c * K_ + k] = f2bf(cb[(size_t)k * C_ + c]);
}

// z_q = attn(bf16) @ cb(bf16) via MFMA 16x16x32; x_d = z_q; vq_loss fused.
// Block: 64 rows x 256 cols; wave: 64 rows x 64 cols = 4x4 16x16 tiles.
__global__ __launch_bounds__(256) void zq_kernel(const float* __restrict__ x,
                                                 const unsigned short* __restrict__ att,
                                                 const unsigned short* __restrict__ cbt,
                                                 float* __restrict__ out,
                                                 float* __restrict__ scal) {
  int tid = threadIdx.x;
  int wv = tid >> 6, lane = tid & 63;
  int r0 = blockIdx.x * 64;
  int c0 = blockIdx.y * 256 + wv * 64;
  int nb = r0 >> 10, t0 = r0 & 1023;
  int ll = lane & 15, lh = (lane >> 4) * 8;

  // A-frag: A[m][k], m=lane&15, k=(lane>>4)*8+j  -> 16B contiguous global load
  const unsigned short* abase = att + (size_t)(r0 + ll) * K_ + lh;
  // B-frag: B[k][n], n=lane&15, k=(lane>>4)*8+j  -> cbT[n][k] 16B contiguous
  const unsigned short* bbase = cbt + (size_t)(c0 + ll) * K_ + lh;

  f32x4 acc[4][4] = {};
  short8 a0[4], b0[4], a1[4], b1[4];
#pragma unroll
  for (int rt = 0; rt < 4; ++rt) a0[rt] = *(const short8*)(abase + (size_t)rt * 16 * K_);
#pragma unroll
  for (int ct = 0; ct < 4; ++ct) b0[ct] = *(const short8*)(bbase + (size_t)ct * 16 * K_);

  for (int k0 = 0; k0 < K_; k0 += 64) {
#pragma unroll
    for (int rt = 0; rt < 4; ++rt)
      a1[rt] = *(const short8*)(abase + (size_t)rt * 16 * K_ + k0 + 32);
#pragma unroll
    for (int ct = 0; ct < 4; ++ct)
      b1[ct] = *(const short8*)(bbase + (size_t)ct * 16 * K_ + k0 + 32);
#pragma unroll
    for (int rt = 0; rt < 4; ++rt)
#pragma unroll
      for (int ct = 0; ct < 4; ++ct)
        acc[rt][ct] = __builtin_amdgcn_mfma_f32_16x16x32_bf16(a0[rt], b0[ct], acc[rt][ct], 0, 0, 0);
    if (k0 + 64 < K_) {
#pragma unroll
      for (int rt = 0; rt < 4; ++rt)
        a0[rt] = *(const short8*)(abase + (size_t)rt * 16 * K_ + k0 + 64);
#pragma unroll
      for (int ct = 0; ct < 4; ++ct)
        b0[ct] = *(const short8*)(bbase + (size_t)ct * 16 * K_ + k0 + 64);
    }
#pragma unroll
    for (int rt = 0; rt < 4; ++rt)
#pragma unroll
      for (int ct = 0; ct < 4; ++ct)
        acc[rt][ct] = __builtin_amdgcn_mfma_f32_16x16x32_bf16(a1[rt], b1[ct], acc[rt][ct], 0, 0, 0);
  }

  // C/D layout: col = lane&15, row = (lane>>4)*4 + reg  (4 consecutive t's/lane)
  float vqp = 0.f;
#pragma unroll
  for (int rt = 0; rt < 4; ++rt) {
    int t = t0 + rt * 16 + (lane >> 4) * 4;
#pragma unroll
    for (int ct = 0; ct < 4; ++ct) {
      int c = c0 + ct * 16 + ll;
      size_t xi = (size_t)nb * C_ * T_ + (size_t)c * T_ + t;
      float4 xv = *(const float4*)&x[xi];
      float4 z = make_float4(acc[rt][ct][0], acc[rt][ct][1], acc[rt][ct][2], acc[rt][ct][3]);
      float d0 = z.x - xv.x, d1 = z.y - xv.y, d2 = z.z - xv.z, d3 = z.w - xv.w;
      vqp += d0 * d0 + d1 * d1 + d2 * d2 + d3 * d3;
      *(float4*)&out[XD_OFF + xi] = z;   // x_d = xf + (z_q - xf) = z_q
    }
  }
#pragma unroll
  for (int off = 1; off < 64; off <<= 1) vqp += __shfl_xor(vqp, off, 64);
  if (lane == 0) atomicAdd(&scal[1], vqp);
}

__global__ __launch_bounds__(1024) void finalize_kernel(const float* __restrict__ avgp,
                                                        const float* __restrict__ counts,
                                                        const float* __restrict__ scal,
                                                        float* __restrict__ out) {
  __shared__ float r1[16], r2[16];
  int tid = threadIdx.x;
  float a = avgp[tid] * (1.0f / 65536.0f);
  float t1 = a * logf(a + 1e-5f);
  float p = counts[tid] * (1.0f / 65536.0f);
  float t2 = p * logf(p + 1e-7f);
#pragma unroll
  for (int off = 1; off < 64; off <<= 1) {
    t1 += __shfl_xor(t1, off, 64);
    t2 += __shfl_xor(t2, off, 64);
  }
  int wv = tid >> 6, lane = tid & 63;
  if (lane == 0) { r1[wv] = t1; r2[wv] = t2; }
  __syncthreads();
  if (tid == 0) {
    float T1 = 0.f, T2 = 0.f;
    for (int i = 0; i < 16; ++i) { T1 += r1[i]; T2 += r2[i]; }
    float sample_entropy = scal[0] * (1.0f / 65536.0f);
    float avg_entropy = -T1;
    out[SC_OFF + 0] = sample_entropy;
    out[SC_OFF + 1] = avg_entropy;
    out[SC_OFF + 2] = sample_entropy - avg_entropy;
    out[SC_OFF + 3] = expf(-T2);
    out[SC_OFF + 4] = scal[1] * (1.0f / 33554432.0f);
  }
}

extern "C" void kernel_launch(void* const* d_in, const int* in_sizes, int n_in,
                              void* d_out, int out_size, void* d_ws, size_t ws_size,
                              hipStream_t stream) {
  const float* x  = (const float*)d_in[0];
  const float* cb = (const float*)d_in[1];
  const float* Wq = (const float*)d_in[2];
  const float* Wk = (const float*)d_in[3];
  float* out = (float*)d_out;
  float* ws = (float*)d_ws;
  float* q      = ws + Q_OFF;                         // fp32 [NT][512]
  unsigned short* att = (unsigned short*)(ws + Q_OFF); // bf16 [NT][1024] (alias)
  float* knT    = ws + KNT_OFF;                        // fp32 [512][1024]
  unsigned short* cbt = (unsigned short*)(ws + KNT_OFF); // bf16 [512][1024] (alias, post-logits)
  float* avgp   = ws + AVG_OFF;
  float* counts = ws + CNT_OFF;
  float* scal   = ws + SCAL_OFF;

  init_kernel<<<9, 256, 0, stream>>>(avgp);
  knorm_kernel<<<K_ / 4, 256, 0, stream>>>(cb, Wk, knT);
  q_kernel<<<NT_ / 32, 256, 0, stream>>>(x, Wq, q);
  logits_kernel<<<NT_ / 32, 256, 0, stream>>>(q, knT, att, out, avgp, counts, scal);
  cbt_kernel<<<(C_ * K_) / 256, 256, 0, stream>>>(cb, cbt);
  zq_kernel<<<dim3(NT_ / 64, 2), 256, 0, stream>>>(x, att, cbt, out, scal);
  finalize_kernel<<<1, 1024, 0, stream>>>(avgp, counts, scal, out);
}

// Round 3
// 1484.874 us; speedup vs baseline: 2.6557x; 1.4657x over previous
//
#include <hip/hip_runtime.h>
#include <hip/hip_bf16.h>

// Problem dims (fixed by reference)
constexpr int N_ = 64, C_ = 512, T_ = 1024;
constexpr int NT_ = N_ * T_;        // 65536 rows
constexpr int K_ = 1024;            // nb_code
constexpr int A_ = 512;             // attn_dim

// Output layout (floats, concatenated in return order)
constexpr size_t XD_OFF   = 0;                       // 33554432 floats
constexpr size_t SC_OFF   = (size_t)N_ * C_ * T_;    // 5 scalars
constexpr size_t CODE_OFF = SC_OFF + 5;              // 65536 code_idx as float
// NOTE: D~ (fp16 [NT][1024] = 134217728 B) EXACTLY fits the XD region of d_out.
// It is written by d_kernel, consumed by stats_kernel, then zq_kernel
// overwrites the region with x_d (stream-ordered, same launch).

// Workspace layout (floats)
// region0 (128 MB): xhT bf16 [NT][512] (first 64 MB); att bf16 [NT][1024]
//   aliases the same base — xhT is dead once stats_kernel (which writes att)
//   runs, and d_kernel (the only xhT reader) fully precedes it.
constexpr size_t MHT_OFF  = 33554432;                 // MhT bf16 [1024][512]
constexpr size_t MT_OFF   = MHT_OFF + 262144;         // MT fp32 [1024][512]
constexpr size_t WQH_OFF  = MT_OFF + 524288;          // WqhT bf16 [512][512]
constexpr size_t KN_OFF   = WQH_OFF + 131072;         // kn fp32 [1024][512]
constexpr size_t CBT_OFF  = KN_OFF + 524288;          // cbt bf16 [512][1024]
constexpr size_t NSQ_OFF  = CBT_OFF + 262144;         // normsq fp32 [65536]
constexpr size_t AVG_OFF  = NSQ_OFF + 65536;
constexpr size_t CNT_OFF  = AVG_OFF + 1024;
constexpr size_t SCAL_OFF = CNT_OFF + 1024;           // [0]=ent_sum, [1]=vq_sum

typedef __attribute__((ext_vector_type(8))) short short8;
typedef __attribute__((ext_vector_type(4))) float f32x4;
typedef _Float16 h4 __attribute__((ext_vector_type(4)));

__device__ __forceinline__ unsigned short f2bf(float f) {
  unsigned int u = __float_as_uint(f);
  unsigned int r = (u + 0x7fffu + ((u >> 16) & 1u)) >> 16;
  return (unsigned short)r;
}

__global__ __launch_bounds__(256) void init_kernel(float* small, float* nsq) {
  int i = blockIdx.x * 256 + threadIdx.x;
  if (i < 2050) small[i] = 0.f;     // avg_probs + counts + 2 scalars
  if (i < NT_) nsq[i] = 0.f;
}

// kn = l2norm(codebook @ Wk), row-major [1024][512] (NO 1/sqrt(A) fold)
__global__ __launch_bounds__(256) void knorm_kernel(const float* __restrict__ cb,
                                                    const float* __restrict__ Wk,
                                                    float* __restrict__ kn) {
  __shared__ float cb_s[4][A_];
  __shared__ float norm_s[4];
  int tid = threadIdx.x;
  int r0 = blockIdx.x * 4;
  for (int i = tid; i < 4 * A_; i += 256) {
    int r = i >> 9, c = i & 511;
    cb_s[r][c] = cb[(size_t)(r0 + r) * C_ + c];
  }
  if (tid < 4) norm_s[tid] = 0.f;
  __syncthreads();
  float acc[4][2] = {};
  for (int c = 0; c < C_; ++c) {
    float w0 = Wk[(size_t)c * A_ + tid];
    float w1 = Wk[(size_t)c * A_ + tid + 256];
#pragma unroll
    for (int r = 0; r < 4; ++r) {
      float xv = cb_s[r][c];
      acc[r][0] += xv * w0;
      acc[r][1] += xv * w1;
    }
  }
#pragma unroll
  for (int r = 0; r < 4; ++r) {
    float ss = acc[r][0] * acc[r][0] + acc[r][1] * acc[r][1];
#pragma unroll
    for (int off = 32; off > 0; off >>= 1) ss += __shfl_down(ss, off, 64);
    if ((tid & 63) == 0) atomicAdd(&norm_s[r], ss);
  }
  __syncthreads();
#pragma unroll
  for (int r = 0; r < 4; ++r) {
    float scale = 1.0f / (sqrtf(norm_s[r]) + 1e-8f);
    kn[(size_t)(r0 + r) * A_ + tid] = acc[r][0] * scale;
    kn[(size_t)(r0 + r) * A_ + tid + 256] = acc[r][1] * scale;
  }
}

// M = Wq @ kn^T  (fp64 accumulate), outputs MhT bf16 [j][c] and MT fp32 [j][c]
__global__ __launch_bounds__(256) void m_kernel(const float* __restrict__ Wq,
                                                const float* __restrict__ kn,
                                                unsigned short* __restrict__ MhT,
                                                float* __restrict__ MT) {
  __shared__ float kn_s[4][512];
  int tid = threadIdx.x;
  int j0 = blockIdx.x * 4;
  for (int i = tid; i < 4 * 512; i += 256) {
    int jj = i >> 9, a = i & 511;
    kn_s[jj][a] = kn[(size_t)(j0 + jj) * 512 + a];
  }
  __syncthreads();
  double acc[2][4] = {};
  for (int a0 = 0; a0 < 512; a0 += 4) {
    float4 w0 = *(const float4*)&Wq[(size_t)tid * 512 + a0];
    float4 w1 = *(const float4*)&Wq[(size_t)(tid + 256) * 512 + a0];
#pragma unroll
    for (int jj = 0; jj < 4; ++jj) {
      float4 kv = *(float4*)&kn_s[jj][a0];
      acc[0][jj] += (double)w0.x * kv.x + (double)w0.y * kv.y +
                    (double)w0.z * kv.z + (double)w0.w * kv.w;
      acc[1][jj] += (double)w1.x * kv.x + (double)w1.y * kv.y +
                    (double)w1.z * kv.z + (double)w1.w * kv.w;
    }
  }
#pragma unroll
  for (int jj = 0; jj < 4; ++jj) {
    int j = j0 + jj;
    float m0 = (float)acc[0][jj], m1 = (float)acc[1][jj];
    MhT[(size_t)j * 512 + tid] = f2bf(m0);
    MhT[(size_t)j * 512 + tid + 256] = f2bf(m1);
    MT[(size_t)j * 512 + tid] = m0;
    MT[(size_t)j * 512 + tid + 256] = m1;
  }
}

// WqhT[j][c] = bf16(Wq[c][j])
__global__ __launch_bounds__(256) void wqht_kernel(const float* __restrict__ Wq,
                                                   unsigned short* __restrict__ WqhT) {
  int idx = blockIdx.x * 256 + threadIdx.x;   // 262144
  int j = idx >> 9, c = idx & 511;
  WqhT[idx] = f2bf(Wq[(size_t)c * 512 + j]);
}

// cbT[c][k] = bf16(cb[k][c]) — B operand for the z_q MFMA
__global__ __launch_bounds__(256) void cbt_kernel(const float* __restrict__ cb,
                                                  unsigned short* __restrict__ cbt) {
  int idx = blockIdx.x * 256 + threadIdx.x;   // 524288 total
  int c = idx >> 10, k = idx & 1023;
  cbt[(size_t)c * K_ + k] = f2bf(cb[(size_t)k * C_ + c]);
}

// xhT[row][c] = bf16(x[n][c][t]),  row = n*1024 + t  (LDS transpose)
__global__ __launch_bounds__(256) void xsplit_kernel(const float* __restrict__ x,
                                                     unsigned short* __restrict__ xhT) {
  __shared__ float tile[64][65];
  int tid = threadIdx.x;
  int n = blockIdx.x >> 4;
  int t0 = (blockIdx.x & 15) * 64;
  for (int c0 = 0; c0 < 512; c0 += 64) {
    __syncthreads();
    {
      int t = tid & 63, cg = tid >> 6;
#pragma unroll
      for (int cl = 0; cl < 16; ++cl) {
        int cc = cl * 4 + cg;
        tile[cc][t] = x[(((size_t)(n * 512 + c0 + cc)) << 10) + t0 + t];
      }
    }
    __syncthreads();
    {
      int c = tid & 63, tg = tid >> 6;
#pragma unroll
      for (int tl = 0; tl < 16; ++tl) {
        int tt = tl * 4 + tg;
        xhT[(((size_t)(n * 1024 + t0 + tt)) << 9) + c0 + c] = f2bf(tile[c][tt]);
      }
    }
  }
}

// D~ = xh @ Mh (y<4) fp16->d_out region; q-norms via xh @ Wqh (y>=4).
// Block 64 rows x 256 cols, wave 64x64, direct global->frag, no LDS/barriers.
__global__ __launch_bounds__(256) void d_kernel(const unsigned short* __restrict__ xhT,
                                                const unsigned short* __restrict__ MhT,
                                                const unsigned short* __restrict__ WqhT,
                                                _Float16* __restrict__ D16,
                                                float* __restrict__ nsq) {
  int tid = threadIdx.x;
  int wv = tid >> 6, lane = tid & 63;
  int r0 = blockIdx.x * 64;
  int y = blockIdx.y;
  bool isq = (y >= 4);
  int c0 = (isq ? (y - 4) : y) * 256 + wv * 64;
  int ll = lane & 15, lh = (lane >> 4) * 8;

  const unsigned short* abase = xhT + (((size_t)(r0 + ll)) << 9) + lh;
  const unsigned short* BT = isq ? WqhT : MhT;
  const unsigned short* bbase = BT + (((size_t)(c0 + ll)) << 9) + lh;

  f32x4 acc[4][4] = {};
  short8 a0[4], b0[4], a1[4], b1[4];
#pragma unroll
  for (int rt = 0; rt < 4; ++rt) a0[rt] = *(const short8*)(abase + (size_t)rt * 8192);
#pragma unroll
  for (int ct = 0; ct < 4; ++ct) b0[ct] = *(const short8*)(bbase + (size_t)ct * 8192);

  for (int k0 = 0; k0 < 512; k0 += 64) {
#pragma unroll
    for (int rt = 0; rt < 4; ++rt)
      a1[rt] = *(const short8*)(abase + (size_t)rt * 8192 + k0 + 32);
#pragma unroll
    for (int ct = 0; ct < 4; ++ct)
      b1[ct] = *(const short8*)(bbase + (size_t)ct * 8192 + k0 + 32);
#pragma unroll
    for (int rt = 0; rt < 4; ++rt)
#pragma unroll
      for (int ct = 0; ct < 4; ++ct)
        acc[rt][ct] = __builtin_amdgcn_mfma_f32_16x16x32_bf16(a0[rt], b0[ct], acc[rt][ct], 0, 0, 0);
    if (k0 + 64 < 512) {
#pragma unroll
      for (int rt = 0; rt < 4; ++rt)
        a0[rt] = *(const short8*)(abase + (size_t)rt * 8192 + k0 + 64);
#pragma unroll
      for (int ct = 0; ct < 4; ++ct)
        b0[ct] = *(const short8*)(bbase + (size_t)ct * 8192 + k0 + 64);
    }
#pragma unroll
    for (int rt = 0; rt < 4; ++rt)
#pragma unroll
      for (int ct = 0; ct < 4; ++ct)
        acc[rt][ct] = __builtin_amdgcn_mfma_f32_16x16x32_bf16(a1[rt], b1[ct], acc[rt][ct], 0, 0, 0);
  }

  // C/D layout: col = c0 + ct*16 + (lane&15), row = r0 + rt*16 + (lane>>4)*4 + reg
  if (!isq) {
#pragma unroll
    for (int rt = 0; rt < 4; ++rt)
#pragma unroll
      for (int ct = 0; ct < 4; ++ct) {
        int col = c0 + ct * 16 + ll;
#pragma unroll
        for (int reg = 0; reg < 4; ++reg) {
          int row = r0 + rt * 16 + (lane >> 4) * 4 + reg;
          D16[(size_t)row * 1024 + col] = (_Float16)acc[rt][ct][reg];
        }
      }
  } else {
#pragma unroll
    for (int rt = 0; rt < 4; ++rt)
#pragma unroll
      for (int reg = 0; reg < 4; ++reg) {
        float sq = 0.f;
#pragma unroll
        for (int ct = 0; ct < 4; ++ct) { float v = acc[rt][ct][reg]; sq += v * v; }
        sq += __shfl_xor(sq, 1, 64);
        sq += __shfl_xor(sq, 2, 64);
        sq += __shfl_xor(sq, 4, 64);
        sq += __shfl_xor(sq, 8, 64);
        if (ll == 0)
          atomicAdd(&nsq[r0 + rt * 16 + (lane >> 4) * 4 + reg], sq);
      }
  }
}

// Stats: load D~ row, scale by s_row -> logits; top-8 by D~; exact fp32
// recheck of candidates (raw x + MT) -> argmax; softmax x2 + entropy +
// avg_probs; attn bf16 -> att (aliases dead xhT).
__global__ __launch_bounds__(256) void stats_kernel(
    const float* __restrict__ x, const _Float16* __restrict__ D16,
    const float* __restrict__ nsq, const float* __restrict__ MT,
    unsigned short* __restrict__ att, float* __restrict__ out,
    float* __restrict__ avg_probs, float* __restrict__ counts,
    float* __restrict__ scal) {
  __shared__ float avg_s[K_];
  __shared__ float red_s;
  int tid = threadIdx.x;
  int wv = tid >> 6, lane = tid & 63;
  int r0 = blockIdx.x * 32;
  for (int i = tid; i < K_; i += 256) avg_s[i] = 0.f;
  if (tid == 0) red_s = 0.f;
  __syncthreads();

  float entp = 0.f;
  float p_loc[16] = {};
  for (int i = 0; i < 8; ++i) {
    int row = r0 + wv * 8 + i;
    int nrow = row >> 10, trow = row & 1023;
    float s = 1.0f / ((sqrtf(nsq[row]) + 1e-8f) * 22.62741699796952f);
    // load logits (16 per lane: kk = lane*4 + kl + 256*kj)
    float l[16];
#pragma unroll
    for (int kj = 0; kj < 4; ++kj) {
      h4 v = *(const h4*)&D16[(size_t)row * 1024 + lane * 4 + kj * 256];
#pragma unroll
      for (int u = 0; u < 4; ++u) l[kj * 4 + u] = (float)v[u] * s;
    }
    // top-8 selection on D~-logits
    float w[16];
#pragma unroll
    for (int k = 0; k < 16; ++k) w[k] = l[k];
    int cand[8];
    float m0 = 0.f;
#pragma unroll
    for (int it = 0; it < 8; ++it) {
      float m = w[0];
      int bidx = lane * 4;
#pragma unroll
      for (int kj = 0; kj < 4; ++kj)
#pragma unroll
        for (int kl = 0; kl < 4; ++kl) {
          float v = w[kj * 4 + kl];
          int kk = lane * 4 + kl + 256 * kj;
          if (v > m || (v == m && kk < bidx)) { m = v; bidx = kk; }
        }
#pragma unroll
      for (int off = 1; off < 64; off <<= 1) {
        float vm = __shfl_xor(m, off, 64);
        int vi = __shfl_xor(bidx, off, 64);
        if (vm > m || (vm == m && vi < bidx)) { m = vm; bidx = vi; }
      }
      if (it == 0) m0 = m;
      cand[it] = bidx;
      if (((bidx >> 2) & 63) == lane) w[(bidx >> 8) * 4 + (bidx & 3)] = -1e30f;
    }
    // x row into regs (c = lane + 64u)
    float xr[8];
#pragma unroll
    for (int u = 0; u < 8; ++u)
      xr[u] = x[(((size_t)(nrow * 512 + lane + u * 64)) << 10) + trow];
    // exact recheck of candidates
    float best = -1e30f;
    int bi = K_;
#pragma unroll
    for (int it = 0; it < 8; ++it) {
      int j = cand[it];
      const float* mrow = &MT[((size_t)j) << 9];
      float sd = 0.f;
#pragma unroll
      for (int u = 0; u < 8; ++u) sd = fmaf(xr[u], mrow[lane + u * 64], sd);
#pragma unroll
      for (int off = 1; off < 64; off <<= 1) sd += __shfl_xor(sd, off, 64);
      if (sd > best || (sd == best && j < bi)) { best = sd; bi = j; }
    }
    if (lane == 0) {
      out[CODE_OFF + row] = (float)bi;
      atomicAdd(&counts[bi], 1.0f);
    }
    // softmax stats (shift by m0)
    float S1 = 0.f, S100 = 0.f, U100 = 0.f;
#pragma unroll
    for (int k = 0; k < 16; ++k) {
      float e = l[k] - m0;
      S1 += __expf(e);
      float e100 = e * 100.0f;
      float p = __expf(e100);
      S100 += p;
      U100 += p * e100;
    }
#pragma unroll
    for (int off = 1; off < 64; off <<= 1) {
      S1 += __shfl_xor(S1, off, 64);
      S100 += __shfl_xor(S100, off, 64);
      U100 += __shfl_xor(U100, off, 64);
    }
    float invS1 = 1.0f / S1;
    float invS100 = 1.0f / S100;
    if (lane == 0) entp += __logf(S100) - U100 * invS100;
#pragma unroll
    for (int kj = 0; kj < 4; ++kj) {
      ushort4 pk;
      float e0 = l[kj * 4 + 0] - m0, e1 = l[kj * 4 + 1] - m0;
      float e2 = l[kj * 4 + 2] - m0, e3 = l[kj * 4 + 3] - m0;
      pk.x = f2bf(__expf(e0) * invS1); pk.y = f2bf(__expf(e1) * invS1);
      pk.z = f2bf(__expf(e2) * invS1); pk.w = f2bf(__expf(e3) * invS1);
      *(ushort4*)&att[(size_t)row * K_ + lane * 4 + kj * 256] = pk;
      p_loc[kj * 4 + 0] += __expf(e0 * 100.f) * invS100;
      p_loc[kj * 4 + 1] += __expf(e1 * 100.f) * invS100;
      p_loc[kj * 4 + 2] += __expf(e2 * 100.f) * invS100;
      p_loc[kj * 4 + 3] += __expf(e3 * 100.f) * invS100;
    }
  }
#pragma unroll
  for (int kj = 0; kj < 4; ++kj)
#pragma unroll
    for (int kl = 0; kl < 4; ++kl)
      atomicAdd(&avg_s[lane * 4 + kl + 256 * kj], p_loc[kj * 4 + kl]);
  if (lane == 0) atomicAdd(&red_s, entp);
  __syncthreads();
  if (tid == 0) atomicAdd(&scal[0], red_s);
  for (int i = tid; i < K_; i += 256) atomicAdd(&avg_probs[i], avg_s[i]);
}

// z_q = attn(bf16) @ cb(bf16) via MFMA; x_d = z_q; vq_loss fused. (unchanged)
__global__ __launch_bounds__(256) void zq_kernel(const float* __restrict__ x,
                                                 const unsigned short* __restrict__ att,
                                                 const unsigned short* __restrict__ cbt,
                                                 float* __restrict__ out,
                                                 float* __restrict__ scal) {
  int tid = threadIdx.x;
  int wv = tid >> 6, lane = tid & 63;
  int r0 = blockIdx.x * 64;
  int c0 = blockIdx.y * 256 + wv * 64;
  int nb = r0 >> 10, t0 = r0 & 1023;
  int ll = lane & 15, lh = (lane >> 4) * 8;

  const unsigned short* abase = att + (size_t)(r0 + ll) * K_ + lh;
  const unsigned short* bbase = cbt + (size_t)(c0 + ll) * K_ + lh;

  f32x4 acc[4][4] = {};
  short8 a0[4], b0[4], a1[4], b1[4];
#pragma unroll
  for (int rt = 0; rt < 4; ++rt) a0[rt] = *(const short8*)(abase + (size_t)rt * 16 * K_);
#pragma unroll
  for (int ct = 0; ct < 4; ++ct) b0[ct] = *(const short8*)(bbase + (size_t)ct * 16 * K_);

  for (int k0 = 0; k0 < K_; k0 += 64) {
#pragma unroll
    for (int rt = 0; rt < 4; ++rt)
      a1[rt] = *(const short8*)(abase + (size_t)rt * 16 * K_ + k0 + 32);
#pragma unroll
    for (int ct = 0; ct < 4; ++ct)
      b1[ct] = *(const short8*)(bbase + (size_t)ct * 16 * K_ + k0 + 32);
#pragma unroll
    for (int rt = 0; rt < 4; ++rt)
#pragma unroll
      for (int ct = 0; ct < 4; ++ct)
        acc[rt][ct] = __builtin_amdgcn_mfma_f32_16x16x32_bf16(a0[rt], b0[ct], acc[rt][ct], 0, 0, 0);
    if (k0 + 64 < K_) {
#pragma unroll
      for (int rt = 0; rt < 4; ++rt)
        a0[rt] = *(const short8*)(abase + (size_t)rt * 16 * K_ + k0 + 64);
#pragma unroll
      for (int ct = 0; ct < 4; ++ct)
        b0[ct] = *(const short8*)(bbase + (size_t)ct * 16 * K_ + k0 + 64);
    }
#pragma unroll
    for (int rt = 0; rt < 4; ++rt)
#pragma unroll
      for (int ct = 0; ct < 4; ++ct)
        acc[rt][ct] = __builtin_amdgcn_mfma_f32_16x16x32_bf16(a1[rt], b1[ct], acc[rt][ct], 0, 0, 0);
  }

  float vqp = 0.f;
#pragma unroll
  for (int rt = 0; rt < 4; ++rt) {
    int t = t0 + rt * 16 + (lane >> 4) * 4;
#pragma unroll
    for (int ct = 0; ct < 4; ++ct) {
      int c = c0 + ct * 16 + ll;
      size_t xi = (size_t)nb * C_ * T_ + (size_t)c * T_ + t;
      float4 xv = *(const float4*)&x[xi];
      float4 z = make_float4(acc[rt][ct][0], acc[rt][ct][1], acc[rt][ct][2], acc[rt][ct][3]);
      float d0 = z.x - xv.x, d1 = z.y - xv.y, d2 = z.z - xv.z, d3 = z.w - xv.w;
      vqp += d0 * d0 + d1 * d1 + d2 * d2 + d3 * d3;
      *(float4*)&out[XD_OFF + xi] = z;
    }
  }
#pragma unroll
  for (int off = 1; off < 64; off <<= 1) vqp += __shfl_xor(vqp, off, 64);
  if (lane == 0) atomicAdd(&scal[1], vqp);
}

__global__ __launch_bounds__(1024) void finalize_kernel(const float* __restrict__ avgp,
                                                        const float* __restrict__ counts,
                                                        const float* __restrict__ scal,
                                                        float* __restrict__ out) {
  __shared__ float r1[16], r2[16];
  int tid = threadIdx.x;
  float a = avgp[tid] * (1.0f / 65536.0f);
  float t1 = a * logf(a + 1e-5f);
  float p = counts[tid] * (1.0f / 65536.0f);
  float t2 = p * logf(p + 1e-7f);
#pragma unroll
  for (int off = 1; off < 64; off <<= 1) {
    t1 += __shfl_xor(t1, off, 64);
    t2 += __shfl_xor(t2, off, 64);
  }
  int wv = tid >> 6, lane = tid & 63;
  if (lane == 0) { r1[wv] = t1; r2[wv] = t2; }
  __syncthreads();
  if (tid == 0) {
    float T1 = 0.f, T2 = 0.f;
    for (int i = 0; i < 16; ++i) { T1 += r1[i]; T2 += r2[i]; }
    float sample_entropy = scal[0] * (1.0f / 65536.0f);
    float avg_entropy = -T1;
    out[SC_OFF + 0] = sample_entropy;
    out[SC_OFF + 1] = avg_entropy;
    out[SC_OFF + 2] = sample_entropy - avg_entropy;
    out[SC_OFF + 3] = expf(-T2);
    out[SC_OFF + 4] = scal[1] * (1.0f / 33554432.0f);
  }
}

extern "C" void kernel_launch(void* const* d_in, const int* in_sizes, int n_in,
                              void* d_out, int out_size, void* d_ws, size_t ws_size,
                              hipStream_t stream) {
  const float* x  = (const float*)d_in[0];
  const float* cb = (const float*)d_in[1];
  const float* Wq = (const float*)d_in[2];
  const float* Wk = (const float*)d_in[3];
  float* out = (float*)d_out;
  float* ws = (float*)d_ws;

  unsigned short* xhT = (unsigned short*)ws;            // bf16 [NT][512]
  unsigned short* att = (unsigned short*)ws;            // bf16 [NT][1024] (alias, post-d_kernel)
  unsigned short* MhT = (unsigned short*)(ws + MHT_OFF);
  float* MT           = ws + MT_OFF;
  unsigned short* WqhT = (unsigned short*)(ws + WQH_OFF);
  float* kn           = ws + KN_OFF;
  unsigned short* cbt = (unsigned short*)(ws + CBT_OFF);
  float* nsq          = ws + NSQ_OFF;
  float* avgp         = ws + AVG_OFF;
  float* counts       = ws + CNT_OFF;
  float* scal         = ws + SCAL_OFF;
  _Float16* D16       = (_Float16*)d_out;               // fp16 [NT][1024] == XD region

  init_kernel<<<256, 256, 0, stream>>>(avgp, nsq);
  knorm_kernel<<<K_ / 4, 256, 0, stream>>>(cb, Wk, kn);
  m_kernel<<<K_ / 4, 256, 0, stream>>>(Wq, kn, MhT, MT);
  wqht_kernel<<<1024, 256, 0, stream>>>(Wq, WqhT);
  cbt_kernel<<<(C_ * K_) / 256, 256, 0, stream>>>(cb, cbt);
  xsplit_kernel<<<1024, 256, 0, stream>>>(x, xhT);
  d_kernel<<<dim3(NT_ / 64, 6), 256, 0, stream>>>(xhT, MhT, WqhT, D16, nsq);
  stats_kernel<<<NT_ / 32, 256, 0, stream>>>(x, D16, nsq, MT, att, out, avgp, counts, scal);
  zq_kernel<<<dim3(NT_ / 64, 2), 256, 0, stream>>>(x, att, cbt, out, scal);
  finalize_kernel<<<1, 1024, 0, stream>>>(avgp, counts, scal, out);
}